// Round 3
// baseline (6509.258 us; speedup 1.0000x reference)
//
#include <hip/hip_runtime.h>
#include <stdint.h>

#define NLAYER 12
#define NH 12
#define DH 64
#define DMODEL 768
#define DI 3072
#define NV 10000
#define QLEN 512
#define MLEN 512
#define CLEN 32
#define BSZ 4
#define KLEN (CLEN + MLEN + QLEN)   // 1056
#define MQ (QLEN * BSZ)             // 2048
#define MK (KLEN * BSZ)             // 4224
#define H3 (3 * NH * DH)            // 2304
#define HD (NH * DH)                // 768
#define NG (BSZ * NH)               // 48 batched-attention groups
#define SROW ((size_t)QLEN * KLEN)  // score elems per group: 512*1056
#define KPAD_R 1152                 // rbuf/kh rows padded to 9*128
#define NPAD_V 10112                // proj cols padded to 79*128
#define NGC 24                      // attention group chunk

typedef __bf16 bf16;
typedef __bf16 bf16x8 __attribute__((ext_vector_type(8)));
typedef float f32x4 __attribute__((ext_vector_type(4)));

// async global -> LDS, 16B per lane (dest must be linear: wave base + lane*16)
__device__ __forceinline__ void gload16(const void* g, void* l) {
    __builtin_amdgcn_global_load_lds((const __attribute__((address_space(1))) void*)g,
                                     (__attribute__((address_space(3))) void*)l, 16, 0, 0);
}

// x = hi + lo split store (hi = RNE bf16(x); lo = bf16(x - hi))
__device__ __forceinline__ void split_store(float x, bf16* __restrict__ hp,
                                            bf16* __restrict__ lp, size_t off) {
    bf16 h = (bf16)x;
    hp[off] = h;
    lp[off] = (bf16)(x - (float)h);
}

// XCD-bijective + GRPM=4 row-grouped rasterization (T1 + panel-band L2 reuse)
__device__ __forceinline__ void raster(int& bx, int& by) {
    int gx = gridDim.x, gy = gridDim.y;
    int nwg = gx * gy;
    int wgid = blockIdx.y * gx + blockIdx.x;
    int q = nwg >> 3, r = nwg & 7;
    int xcd = wgid & 7, lin = wgid >> 3;
    int swz = (xcd < r ? xcd * (q + 1) : r * (q + 1) + (xcd - r) * q) + lin;
    int gsz = gx * 4;
    int grp = swz / gsz, rem = swz % gsz;
    int rows = gy - grp * 4;
    if (rows > 4) rows = 4;
    bx = rem / rows;
    by = grp * 4 + rem % rows;
}

// ---------------- embedding: h = emb[x] * sqrt(D) ----------------
__global__ __launch_bounds__(256) void k_embed(const int* __restrict__ x,
                                               const float* __restrict__ emb,
                                               float* __restrict__ h) {
    int idx = blockIdx.x * 256 + threadIdx.x;
    if (idx >= MQ * DMODEL) return;
    int row = idx / DMODEL;
    int d = idx % DMODEL;
    int tok = x[row];
    h[idx] = emb[(size_t)tok * DMODEL + d] * 27.712812921102035f;  // sqrt(768)
}

// ---------------- sinusoidal position embedding -> bf16 hi/lo planes [KPAD_R][D] ------------
__global__ __launch_bounds__(256) void k_posemb(bf16* __restrict__ rh, bf16* __restrict__ rl) {
    int idx = blockIdx.x * 256 + threadIdx.x;
    if (idx >= KPAD_R * DMODEL) return;
    int k = idx / DMODEL;
    int d = idx % DMODEL;
    float v = 0.0f;
    if (k < KLEN) {
        int pos = KLEN - 1 - k;
        int j = (d < DMODEL / 2) ? d : d - DMODEL / 2;
        double inv = exp(-((double)(2 * j) / (double)DMODEL) * log(10000.0));
        double s = (double)pos * inv;
        v = (d < DMODEL / 2) ? (float)sin(s) : (float)cos(s);
    }
    split_store(v, rh, rl, (size_t)idx);
}

// ---------------- zero the pad rows (1056..1151) of kh planes, once ----------------
__global__ __launch_bounds__(256) void k_zpad(bf16* __restrict__ khH, bf16* __restrict__ khL) {
    int idx = blockIdx.x * 256 + threadIdx.x;
    int tot = NG * (KPAD_R - KLEN) * DH;
    if (idx >= tot) return;
    int g = idx / ((KPAD_R - KLEN) * DH);
    int rem = idx % ((KPAD_R - KLEN) * DH);
    int jr = rem / DH, d = rem % DH;
    size_t off = ((size_t)g * KPAD_R + KLEN + jr) * DH + d;
    khH[off] = (bf16)0.0f;
    khL[off] = (bf16)0.0f;
}

// ---------------- concat [condition; mems[l]; h] -> bf16 hi/lo planes ----------------
__global__ __launch_bounds__(256) void k_concat(const float* __restrict__ cond,
                                                const float* __restrict__ mem_l,
                                                const float* __restrict__ h,
                                                bf16* __restrict__ catH,
                                                bf16* __restrict__ catL) {
    int idx = blockIdx.x * 256 + threadIdx.x;
    if (idx >= MK * DMODEL) return;
    int row = idx / DMODEL;
    int k = row / BSZ;
    float v;
    if (k < CLEN) v = cond[idx];
    else if (k < CLEN + MLEN) v = mem_l[idx - CLEN * BSZ * DMODEL];
    else v = h[idx - (CLEN + MLEN) * BSZ * DMODEL];
    split_store(v, catH, catL, (size_t)idx);
}

// ---------------- weight transpose + split: W[K][N] fp32 -> Bt_hi/lo[Npad][K] bf16 ----------
__global__ __launch_bounds__(256) void k_wconv(const float* __restrict__ W,
                                               bf16* __restrict__ Bh,
                                               bf16* __restrict__ Bl,
                                               int K, int N) {
    __shared__ float t[32][33];
    int n0 = blockIdx.x * 32, k0 = blockIdx.y * 32;
    int tc = threadIdx.x & 31, tr = threadIdx.x >> 5;
#pragma unroll
    for (int i = 0; i < 32; i += 8) {
        int n = n0 + tc;
        t[tr + i][tc] = (n < N) ? W[(size_t)(k0 + tr + i) * N + n] : 0.0f;
    }
    __syncthreads();
#pragma unroll
    for (int i = 0; i < 32; i += 8) {
        int n = n0 + tr + i;
        int k = k0 + tc;
        float x = t[tc][tr + i];
        size_t off = (size_t)n * K + k;
        bf16 h = (bf16)x;
        Bh[off] = h;
        Bl[off] = (bf16)(x - (float)h);
    }
}

// ---------------- split-bf16 MFMA GEMM: C[M,N] = A[M,K] @ B^T[N,K] (+bias)(+relu) -----------
// BM in {128, 64}; BN fixed 128. SK-way split-K writes partial sums to C + z*M*ldc.
template <int BM, bool BIAS, bool RELU, bool SPLITOUT, int SK>
__global__ __launch_bounds__(256) void k_mgemm(const bf16* __restrict__ Ahi,
                                               const bf16* __restrict__ Alo,
                                               const bf16* __restrict__ Bhi,
                                               const bf16* __restrict__ Blo,
                                               const float* __restrict__ bias,
                                               float* __restrict__ C,
                                               bf16* __restrict__ Chi,
                                               bf16* __restrict__ Clo,
                                               int M, int N, int K, int ldc) {
    constexpr int MI = (BM == 128) ? 4 : 2;
    __shared__ __align__(16) bf16 As[2][BM][32];
    __shared__ __align__(16) bf16 Bs[2][128][32];
    int bx, by;
    raster(bx, by);
    int z = (SK > 1) ? blockIdx.z : 0;
    int kb = K / SK;
    int kbeg = z * kb, kend = kbeg + kb;
    if (SK > 1) C += (size_t)z * M * ldc;
    int tid = threadIdx.x;
    int lane = tid & 63;
    int wave = tid >> 6;
    int bm = by * BM, bn = bx * 128;
    int wr = (wave >> 1) * (BM / 2), wc = (wave & 1) * 64;
    int fr = lane & 15;
    int fk = (lane >> 4) * 8;

    const f32x4 fzero = {0.f, 0.f, 0.f, 0.f};
    f32x4 acc[MI][4];
#pragma unroll
    for (int i = 0; i < MI; i++)
#pragma unroll
        for (int j = 0; j < 4; j++) acc[i][j] = fzero;

    int r0 = tid >> 2, p0 = (tid & 3) * 8;
    int r1 = r0 + 64, p1 = p0;

    for (int k0 = kbeg; k0 < kend; k0 += 32) {
        if (BM == 128) {
            gload16(Ahi + (size_t)(bm + r0) * K + k0 + p0, &As[0][r0][p0]);
            gload16(Ahi + (size_t)(bm + r1) * K + k0 + p1, &As[0][r1 & (BM - 1)][p1]);
            gload16(Alo + (size_t)(bm + r0) * K + k0 + p0, &As[1][r0][p0]);
            gload16(Alo + (size_t)(bm + r1) * K + k0 + p1, &As[1][r1 & (BM - 1)][p1]);
        } else {
            gload16(Ahi + (size_t)(bm + r0) * K + k0 + p0, &As[0][r0 & (BM - 1)][p0]);
            gload16(Alo + (size_t)(bm + r0) * K + k0 + p0, &As[1][r0 & (BM - 1)][p0]);
        }
        gload16(Bhi + (size_t)(bn + r0) * K + k0 + p0, &Bs[0][r0][p0]);
        gload16(Bhi + (size_t)(bn + r1) * K + k0 + p1, &Bs[0][r1][p1]);
        gload16(Blo + (size_t)(bn + r0) * K + k0 + p0, &Bs[1][r0][p0]);
        gload16(Blo + (size_t)(bn + r1) * K + k0 + p1, &Bs[1][r1][p1]);
        __syncthreads();

        bf16x8 ah[MI], al[MI], bh[4], bl[4];
#pragma unroll
        for (int mi = 0; mi < MI; mi++) {
            ah[mi] = *(const bf16x8*)&As[0][wr + mi * 16 + fr][fk];
            al[mi] = *(const bf16x8*)&As[1][wr + mi * 16 + fr][fk];
        }
#pragma unroll
        for (int ni = 0; ni < 4; ni++) {
            bh[ni] = *(const bf16x8*)&Bs[0][wc + ni * 16 + fr][fk];
            bl[ni] = *(const bf16x8*)&Bs[1][wc + ni * 16 + fr][fk];
        }
#pragma unroll
        for (int mi = 0; mi < MI; mi++)
#pragma unroll
            for (int ni = 0; ni < 4; ni++) {
                acc[mi][ni] = __builtin_amdgcn_mfma_f32_16x16x32_bf16(ah[mi], bh[ni], acc[mi][ni], 0, 0, 0);
                acc[mi][ni] = __builtin_amdgcn_mfma_f32_16x16x32_bf16(ah[mi], bl[ni], acc[mi][ni], 0, 0, 0);
                acc[mi][ni] = __builtin_amdgcn_mfma_f32_16x16x32_bf16(al[mi], bh[ni], acc[mi][ni], 0, 0, 0);
            }
        __syncthreads();
    }

#pragma unroll
    for (int mi = 0; mi < MI; mi++) {
        int rowb = bm + wr + mi * 16 + (lane >> 4) * 4;
#pragma unroll
        for (int ni = 0; ni < 4; ni++) {
            int col = bn + wc + ni * 16 + fr;
            if (col >= N) continue;
            float bv = (BIAS && z == 0) ? bias[col] : 0.0f;
#pragma unroll
            for (int r = 0; r < 4; r++) {
                int row = rowb + r;
                if (row >= M) continue;
                float xv = acc[mi][ni][r] + bv;
                if (RELU) xv = fmaxf(xv, 0.0f);
                size_t off = (size_t)row * ldc + col;
                if (SPLITOUT) {
                    bf16 hh = (bf16)xv;
                    Chi[off] = hh;
                    Clo[off] = (bf16)(xv - (float)hh);
                } else {
                    C[off] = xv;
                }
            }
        }
    }
}

// ---------------- qkv GEMM with fused split-plane epilogue ----------------
// MODE 0: Q gemm  (M=2048 h-rows, N=768)  -> qw/qr planes, (q+bias)*0.125
// MODE 1: KV gemm (M=4224 rows,  N=1536)  -> kh planes [g][1152][64], v planes [g][1056][64]
template <int MODE>
__global__ __launch_bounds__(256) void k_mgemm_qkv(const bf16* __restrict__ Ahi,
                                                   const bf16* __restrict__ Alo,
                                                   const bf16* __restrict__ Bhi,
                                                   const bf16* __restrict__ Blo,
                                                   const float* __restrict__ rwb,
                                                   const float* __restrict__ rrb,
                                                   bf16* __restrict__ P0H, bf16* __restrict__ P0L,
                                                   bf16* __restrict__ P1H, bf16* __restrict__ P1L) {
    constexpr int K = DMODEL;
    __shared__ __align__(16) bf16 As[2][128][32];
    __shared__ __align__(16) bf16 Bs[2][128][32];
    int bx, by;
    raster(bx, by);
    int tid = threadIdx.x;
    int lane = tid & 63;
    int wave = tid >> 6;
    int bm = by * 128, bn = bx * 128;
    int wr = (wave >> 1) * 64, wc = (wave & 1) * 64;
    int fr = lane & 15;
    int fk = (lane >> 4) * 8;

    const f32x4 fzero = {0.f, 0.f, 0.f, 0.f};
    f32x4 acc[4][4];
#pragma unroll
    for (int i = 0; i < 4; i++)
#pragma unroll
        for (int j = 0; j < 4; j++) acc[i][j] = fzero;

    int r0 = tid >> 2, p0 = (tid & 3) * 8;
    int r1 = r0 + 64, p1 = p0;

    for (int k0 = 0; k0 < K; k0 += 32) {
        gload16(Ahi + (size_t)(bm + r0) * K + k0 + p0, &As[0][r0][p0]);
        gload16(Ahi + (size_t)(bm + r1) * K + k0 + p1, &As[0][r1][p1]);
        gload16(Alo + (size_t)(bm + r0) * K + k0 + p0, &As[1][r0][p0]);
        gload16(Alo + (size_t)(bm + r1) * K + k0 + p1, &As[1][r1][p1]);
        gload16(Bhi + (size_t)(bn + r0) * K + k0 + p0, &Bs[0][r0][p0]);
        gload16(Bhi + (size_t)(bn + r1) * K + k0 + p1, &Bs[0][r1][p1]);
        gload16(Blo + (size_t)(bn + r0) * K + k0 + p0, &Bs[1][r0][p0]);
        gload16(Blo + (size_t)(bn + r1) * K + k0 + p1, &Bs[1][r1][p1]);
        __syncthreads();

        bf16x8 ah[4], al[4], bh[4], bl[4];
#pragma unroll
        for (int mi = 0; mi < 4; mi++) {
            ah[mi] = *(const bf16x8*)&As[0][wr + mi * 16 + fr][fk];
            al[mi] = *(const bf16x8*)&As[1][wr + mi * 16 + fr][fk];
        }
#pragma unroll
        for (int ni = 0; ni < 4; ni++) {
            bh[ni] = *(const bf16x8*)&Bs[0][wc + ni * 16 + fr][fk];
            bl[ni] = *(const bf16x8*)&Bs[1][wc + ni * 16 + fr][fk];
        }
#pragma unroll
        for (int mi = 0; mi < 4; mi++)
#pragma unroll
            for (int ni = 0; ni < 4; ni++) {
                acc[mi][ni] = __builtin_amdgcn_mfma_f32_16x16x32_bf16(ah[mi], bh[ni], acc[mi][ni], 0, 0, 0);
                acc[mi][ni] = __builtin_amdgcn_mfma_f32_16x16x32_bf16(ah[mi], bl[ni], acc[mi][ni], 0, 0, 0);
                acc[mi][ni] = __builtin_amdgcn_mfma_f32_16x16x32_bf16(al[mi], bh[ni], acc[mi][ni], 0, 0, 0);
            }
        __syncthreads();
    }

#pragma unroll
    for (int mi = 0; mi < 4; mi++) {
        int rowb = bm + wr + mi * 16 + (lane >> 4) * 4;
#pragma unroll
        for (int ni = 0; ni < 4; ni++) {
            int col = bn + wc + ni * 16 + fr;
#pragma unroll
            for (int r = 0; r < 4; r++) {
                int row = rowb + r;
                float xv = acc[mi][ni][r];
                int b = row & 3;
                if (MODE == 0) {
                    int i = row >> 2;
                    int g = b * NH + (col >> 6);
                    int d = col & 63;
                    size_t off = ((size_t)g * QLEN + i) * DH + d;
                    split_store((xv + rwb[col]) * 0.125f, P0H, P0L, off);
                    split_store((xv + rrb[col]) * 0.125f, P1H, P1L, off);
                } else {
                    int j = row >> 2;
                    if (col < HD) {
                        int g = b * NH + (col >> 6);
                        int d = col & 63;
                        split_store(xv, P0H, P0L, ((size_t)g * KPAD_R + j) * DH + d);
                    } else {
                        int c2 = col - HD;
                        int g = b * NH + (c2 >> 6);
                        int d = c2 & 63;
                        split_store(xv, P1H, P1L, ((size_t)g * KLEN + j) * DH + d);
                    }
                }
            }
        }
    }
}

// ---------------- bf16 V transpose: v[g][1056][64] -> vt[gl][64][1056] ----------------
__global__ __launch_bounds__(256) void k_vtconv_b(const bf16* __restrict__ vH,
                                                  const bf16* __restrict__ vL,
                                                  bf16* __restrict__ vtH,
                                                  bf16* __restrict__ vtL,
                                                  int g0) {
    __shared__ bf16 th[32][33], tl[32][33];
    int gl = blockIdx.z;
    int g = g0 + gl;
    int j0 = blockIdx.x * 32, d0 = blockIdx.y * 32;
    int tc = threadIdx.x & 31, tr = threadIdx.x >> 5;
#pragma unroll
    for (int i = 0; i < 32; i += 8) {
        size_t src = ((size_t)g * KLEN + j0 + tr + i) * DH + d0 + tc;
        th[tr + i][tc] = vH[src];
        tl[tr + i][tc] = vL[src];
    }
    __syncthreads();
#pragma unroll
    for (int i = 0; i < 32; i += 8) {
        size_t dst = ((size_t)gl * DH + d0 + tr + i) * KLEN + j0 + tc;
        vtH[dst] = th[tc][tr + i];
        vtL[dst] = tl[tc][tr + i];
    }
}

// ---------------- batched score GEMM (MFMA, split-bf16), K=64, mask-aware skips -------------
// SHIFT=false: sAc[gl][i][t]  = qw . kh   (t < 1056); skip tiles fully masked
// SHIFT=true : sAc[gl][i][t-511+i] += qr . rk ; skip tiles scattering entirely to j<0
template <bool SHIFT>
__global__ __launch_bounds__(256) void k_score(const bf16* __restrict__ QH,
                                               const bf16* __restrict__ QL,
                                               const bf16* __restrict__ KHp,
                                               const bf16* __restrict__ KLp,
                                               float* __restrict__ sAc,
                                               int g0) {
    int bm = blockIdx.y * 128, bn = blockIdx.x * 128;
    if (!SHIFT && bn >= bm + 672) return;     // whole tile masked (t > i+544)
    if (SHIFT && bn + bm < 257) return;       // whole tile scatters to j < 0
    int gl = blockIdx.z;
    int g = g0 + gl;
    int n = g % NH;
    const bf16* Ah = QH + (size_t)g * QLEN * DH;
    const bf16* Al = QL + (size_t)g * QLEN * DH;
    const bf16 *Bh, *Bl;
    int ldb;
    if (SHIFT) { Bh = KHp + n * DH; Bl = KLp + n * DH; ldb = HD; }
    else { Bh = KHp + (size_t)g * KPAD_R * DH; Bl = KLp + (size_t)g * KPAD_R * DH; ldb = DH; }
    float* C = sAc + (size_t)gl * SROW;

    __shared__ __align__(16) bf16 As[2][128][32];
    __shared__ __align__(16) bf16 Bs[2][128][32];
    int tid = threadIdx.x;
    int lane = tid & 63;
    int wave = tid >> 6;
    int wr = (wave >> 1) * 64, wc = (wave & 1) * 64;
    int fr = lane & 15;
    int fk = (lane >> 4) * 8;

    const f32x4 fzero = {0.f, 0.f, 0.f, 0.f};
    f32x4 acc[4][4];
#pragma unroll
    for (int i = 0; i < 4; i++)
#pragma unroll
        for (int j = 0; j < 4; j++) acc[i][j] = fzero;

    int r0 = tid >> 2, p0 = (tid & 3) * 8;
    int r1 = r0 + 64, p1 = p0;

#pragma unroll
    for (int k0 = 0; k0 < DH; k0 += 32) {
        gload16(Ah + (size_t)(bm + r0) * DH + k0 + p0, &As[0][r0][p0]);
        gload16(Ah + (size_t)(bm + r1) * DH + k0 + p1, &As[0][r1][p1]);
        gload16(Al + (size_t)(bm + r0) * DH + k0 + p0, &As[1][r0][p0]);
        gload16(Al + (size_t)(bm + r1) * DH + k0 + p1, &As[1][r1][p1]);
        gload16(Bh + (size_t)(bn + r0) * ldb + k0 + p0, &Bs[0][r0][p0]);
        gload16(Bh + (size_t)(bn + r1) * ldb + k0 + p1, &Bs[0][r1][p1]);
        gload16(Bl + (size_t)(bn + r0) * ldb + k0 + p0, &Bs[1][r0][p0]);
        gload16(Bl + (size_t)(bn + r1) * ldb + k0 + p1, &Bs[1][r1][p1]);
        __syncthreads();

        bf16x8 ah[4], al[4], bh[4], bl[4];
#pragma unroll
        for (int mi = 0; mi < 4; mi++) {
            ah[mi] = *(const bf16x8*)&As[0][wr + mi * 16 + fr][fk];
            al[mi] = *(const bf16x8*)&As[1][wr + mi * 16 + fr][fk];
        }
#pragma unroll
        for (int ni = 0; ni < 4; ni++) {
            bh[ni] = *(const bf16x8*)&Bs[0][wc + ni * 16 + fr][fk];
            bl[ni] = *(const bf16x8*)&Bs[1][wc + ni * 16 + fr][fk];
        }
#pragma unroll
        for (int mi = 0; mi < 4; mi++)
#pragma unroll
            for (int ni = 0; ni < 4; ni++) {
                acc[mi][ni] = __builtin_amdgcn_mfma_f32_16x16x32_bf16(ah[mi], bh[ni], acc[mi][ni], 0, 0, 0);
                acc[mi][ni] = __builtin_amdgcn_mfma_f32_16x16x32_bf16(ah[mi], bl[ni], acc[mi][ni], 0, 0, 0);
                acc[mi][ni] = __builtin_amdgcn_mfma_f32_16x16x32_bf16(al[mi], bh[ni], acc[mi][ni], 0, 0, 0);
            }
        __syncthreads();
    }

#pragma unroll
    for (int mi = 0; mi < 4; mi++) {
        int rowb = bm + wr + mi * 16 + (lane >> 4) * 4;
#pragma unroll
        for (int ni = 0; ni < 4; ni++) {
            int t = bn + wc + ni * 16 + fr;
            if (t >= KLEN) continue;
#pragma unroll
            for (int r = 0; r < 4; r++) {
                int i = rowb + r;
                if (SHIFT) {
                    int j = t - (QLEN - 1) + i;
                    if (j >= 0) C[(size_t)i * KLEN + j] += acc[mi][ni][r];
                } else {
                    C[(size_t)i * KLEN + t] = acc[mi][ni][r];
                }
            }
        }
    }
}

// ---------------- masked softmax: read fp32 scores (pre-scaled), write bf16 probs -----------
__global__ __launch_bounds__(256) void k_softmax_p(const float* __restrict__ sAc,
                                                   bf16* __restrict__ P) {
    __shared__ float red[256];
    int i = blockIdx.x;
    int gl = blockIdx.y;
    int tid = threadIdx.x;
    const float* row = sAc + (size_t)gl * SROW + (size_t)i * KLEN;
    bf16* pr = P + (size_t)gl * SROW + (size_t)i * KLEN;
    int len = i + CLEN + MLEN + 1;
    float v[5];
    int cnt = 0;
    float mx = -1e30f;
    for (int j = tid; j < len; j += 256) {
        float s = row[j];
        v[cnt++] = s;
        mx = fmaxf(mx, s);
    }
    red[tid] = mx;
    __syncthreads();
    for (int st = 128; st > 0; st >>= 1) {
        if (tid < st) red[tid] = fmaxf(red[tid], red[tid + st]);
        __syncthreads();
    }
    float smax = red[0];
    __syncthreads();
    float sum = 0.f;
    cnt = 0;
    for (int j = tid; j < len; j += 256) {
        float e = __expf(v[cnt] - smax);
        v[cnt] = e;
        sum += e;
        cnt++;
    }
    red[tid] = sum;
    __syncthreads();
    for (int st = 128; st > 0; st >>= 1) {
        if (tid < st) red[tid] += red[tid + st];
        __syncthreads();
    }
    float inv = 1.0f / red[0];
    cnt = 0;
    for (int j = tid; j < len; j += 256) pr[j] = (bf16)(v[cnt++] * inv);
    for (int j = tid; j < KLEN; j += 256)
        if (j >= len) pr[j] = (bf16)0.0f;
}

// ---------------- batched AV GEMM (MFMA): attnb = P @ V, K clamped by causal mask ----------
__global__ __launch_bounds__(256) void k_av(const bf16* __restrict__ P,
                                            const bf16* __restrict__ VH,
                                            const bf16* __restrict__ VL,
                                            bf16* __restrict__ atH,
                                            bf16* __restrict__ atL,
                                            int g0) {
    int gl = blockIdx.z;
    int g = g0 + gl;
    int b = g / NH, n = g % NH;
    const bf16* Ap = P + (size_t)gl * SROW;
    const bf16* Vh = VH + (size_t)gl * DH * KLEN;
    const bf16* Vl = VL + (size_t)gl * DH * KLEN;
    __shared__ __align__(16) bf16 As[64][32];
    __shared__ __align__(16) bf16 Bs[2][64][32];
    int tid = threadIdx.x;
    int lane = tid & 63;
    int wave = tid >> 6;
    int bm = blockIdx.y * 64;
    int fr = lane & 15;
    int fk = (lane >> 4) * 8;
    const f32x4 fzero = {0.f, 0.f, 0.f, 0.f};
    f32x4 acc[4] = {fzero, fzero, fzero, fzero};
    int ra = tid >> 2, pa = (tid & 3) * 8;
    int kmax = bm + 608;              // last unmasked col in this row tile (mult of 32)
    if (kmax > KLEN) kmax = KLEN;

    for (int k0 = 0; k0 < kmax; k0 += 32) {
        gload16(Ap + (size_t)(bm + ra) * KLEN + k0 + pa, &As[ra][pa]);
        gload16(Vh + (size_t)ra * KLEN + k0 + pa, &Bs[0][ra][pa]);
        gload16(Vl + (size_t)ra * KLEN + k0 + pa, &Bs[1][ra][pa]);
        __syncthreads();
        bf16x8 a = *(const bf16x8*)&As[wave * 16 + fr][fk];
#pragma unroll
        for (int ni = 0; ni < 4; ni++) {
            bf16x8 bh = *(const bf16x8*)&Bs[0][ni * 16 + fr][fk];
            bf16x8 bl = *(const bf16x8*)&Bs[1][ni * 16 + fr][fk];
            acc[ni] = __builtin_amdgcn_mfma_f32_16x16x32_bf16(a, bh, acc[ni], 0, 0, 0);
            acc[ni] = __builtin_amdgcn_mfma_f32_16x16x32_bf16(a, bl, acc[ni], 0, 0, 0);
        }
        __syncthreads();
    }

#pragma unroll
    for (int ni = 0; ni < 4; ni++) {
        int d = ni * 16 + fr;
#pragma unroll
        for (int r = 0; r < 4; r++) {
            int i = bm + wave * 16 + (lane >> 4) * 4 + r;
            size_t off = (size_t)(i * BSZ + b) * HD + n * DH + d;
            split_store(acc[ni][r], atH, atL, off);
        }
    }
}

// ---------------- h = LN(h + d0 + d1); also emit bf16 hi/lo planes of h ----------------
__global__ __launch_bounds__(256) void k_add_ln(float* __restrict__ h,
                                                const float* __restrict__ d0,
                                                const float* __restrict__ d1,
                                                const float* __restrict__ g,
                                                const float* __restrict__ bta,
                                                bf16* __restrict__ hH,
                                                bf16* __restrict__ hL) {
    __shared__ float xs[DMODEL];
    __shared__ float red[256];
    int row = blockIdx.x;
    int tid = threadIdx.x;
    float* hr = h + (size_t)row * DMODEL;
    const float* dr0 = d0 + (size_t)row * DMODEL;
    const float* dr1 = d1 + (size_t)row * DMODEL;
    float s = 0.f;
    for (int d = tid; d < DMODEL; d += 256) {
        float v = hr[d] + dr0[d] + dr1[d];
        xs[d] = v;
        s += v;
    }
    red[tid] = s;
    __syncthreads();
    for (int st = 128; st > 0; st >>= 1) {
        if (tid < st) red[tid] += red[tid + st];
        __syncthreads();
    }
    float mean = red[0] * (1.0f / DMODEL);
    __syncthreads();
    float v2 = 0.f;
    for (int d = tid; d < DMODEL; d += 256) {
        float t = xs[d] - mean;
        v2 += t * t;
    }
    red[tid] = v2;
    __syncthreads();
    for (int st = 128; st > 0; st >>= 1) {
        if (tid < st) red[tid] += red[tid + st];
        __syncthreads();
    }
    float inv = rsqrtf(red[0] * (1.0f / DMODEL) + 1e-5f);
    for (int d = tid; d < DMODEL; d += 256) {
        float y = (xs[d] - mean) * inv * g[d] + bta[d];
        hr[d] = y;
        split_store(y, hH, hL, (size_t)row * DMODEL + d);
    }
}

extern "C" void kernel_launch(void* const* d_in, const int* in_sizes, int n_in,
                              void* d_out, int out_size, void* d_ws, size_t ws_size,
                              hipStream_t stream) {
    const int* x = (const int*)d_in[0];
    const float* condition = (const float*)d_in[1];
    const float* mems = (const float*)d_in[2];
    const float* emb = (const float*)d_in[3];
    const float* qkv_w = (const float*)d_in[4];
    const float* r_net_w = (const float*)d_in[5];
    const float* o_w = (const float*)d_in[6];
    const float* ln1_g = (const float*)d_in[7];
    const float* ln1_b = (const float*)d_in[8];
    const float* w1 = (const float*)d_in[9];
    const float* b1 = (const float*)d_in[10];
    const float* w2 = (const float*)d_in[11];
    const float* b2 = (const float*)d_in[12];
    const float* ln2_g = (const float*)d_in[13];
    const float* ln2_b = (const float*)d_in[14];
    const float* r_w_bias = (const float*)d_in[15];
    const float* r_r_bias = (const float*)d_in[16];
    const float* proj_w = (const float*)d_in[17];
    const float* proj_b = (const float*)d_in[18];
    float* out = (float*)d_out;

    // ---- fp32 region ----
    float* ws = (float*)d_ws;
    float* h = ws;                                    // 2048*768
    float* delta = h + (size_t)MQ * DMODEL;           // 2 x 2048*768 (split-K pair)
    float* delta2 = delta + (size_t)MQ * DMODEL;

    // ---- persistent bf16 planes ----
    bf16* pb = (bf16*)(delta2 + (size_t)MQ * DMODEL);
    bf16* rbH = pb; pb += (size_t)KPAD_R * DMODEL;
    bf16* rbL = pb; pb += (size_t)KPAD_R * DMODEL;
    bf16* rkH = pb; pb += (size_t)KPAD_R * DMODEL;
    bf16* rkL = pb; pb += (size_t)KPAD_R * DMODEL;
    bf16* atH = pb; pb += (size_t)MQ * HD;
    bf16* atL = pb; pb += (size_t)MQ * HD;
    bf16* qwH = pb; pb += (size_t)NG * QLEN * DH;
    bf16* qwL = pb; pb += (size_t)NG * QLEN * DH;
    bf16* qrH = pb; pb += (size_t)NG * QLEN * DH;
    bf16* qrL = pb; pb += (size_t)NG * QLEN * DH;
    bf16* khH = pb; pb += (size_t)NG * KPAD_R * DH;
    bf16* khL = pb; pb += (size_t)NG * KPAD_R * DH;
    bf16* vH_ = pb; pb += (size_t)NG * KLEN * DH;
    bf16* vL_ = pb; pb += (size_t)NG * KLEN * DH;

    // ---- alias region R: GEMM-side planes XOR attention chunk buffers ----
    // (cat/Bt dead during attention; sA/P/vt dead outside it; hH/hL only live ln->ffn)
    bf16* R = pb;
    bf16* BtH = R;
    bf16* BtL = BtH + (size_t)NPAD_V * DMODEL;
    bf16* ffnH = BtL + (size_t)NPAD_V * DMODEL;
    bf16* ffnL = ffnH + (size_t)MQ * DI;
    bf16* catH = ffnL + (size_t)MQ * DI;
    bf16* catL = catH + (size_t)MK * DMODEL;
    bf16* hH = catL + (size_t)MK * DMODEL;
    bf16* hL = hH + (size_t)MQ * DMODEL;

    float* sAc = (float*)R;                           // NGC*SROW fp32
    bf16* Pc = (bf16*)(sAc + (size_t)NGC * SROW);     // NGC*SROW bf16
    bf16* vtH = Pc + (size_t)NGC * SROW;              // NGC*64*1056
    bf16* vtL = vtH + (size_t)NGC * DH * KLEN;

    dim3 blk(256);
    k_embed<<<dim3((MQ * DMODEL + 255) / 256), blk, 0, stream>>>(x, emb, h);
    k_posemb<<<dim3((KPAD_R * DMODEL + 255) / 256), blk, 0, stream>>>(rbH, rbL);
    k_zpad<<<dim3((NG * (KPAD_R - KLEN) * DH + 255) / 256), blk, 0, stream>>>(khH, khL);

    for (int l = 0; l < NLAYER; l++) {
        k_concat<<<dim3((MK * DMODEL + 255) / 256), blk, 0, stream>>>(
            condition, mems + (size_t)l * MLEN * BSZ * DMODEL, h, catH, catL);

        // qkv projection, fused split-plane epilogues
        k_wconv<<<dim3(H3 / 32, DMODEL / 32), blk, 0, stream>>>(
            qkv_w + (size_t)l * DMODEL * H3, BtH, BtL, DMODEL, H3);
        k_mgemm_qkv<1><<<dim3((2 * HD) / 128, MK / 128), blk, 0, stream>>>(
            catH, catL, BtH + (size_t)HD * DMODEL, BtL + (size_t)HD * DMODEL,
            nullptr, nullptr, khH, khL, vH_, vL_);
        k_mgemm_qkv<0><<<dim3(HD / 128, MQ / 128), blk, 0, stream>>>(
            catH + (size_t)(CLEN + MLEN) * BSZ * DMODEL, catL + (size_t)(CLEN + MLEN) * BSZ * DMODEL,
            BtH, BtL, r_w_bias, r_r_bias, qwH, qwL, qrH, qrL);

        // rk = r @ r_net_w[l] -> split planes [1152][768]
        k_wconv<<<dim3(HD / 32, DMODEL / 32), blk, 0, stream>>>(
            r_net_w + (size_t)l * DMODEL * HD, BtH, BtL, DMODEL, HD);
        k_mgemm<64, false, false, true, 1><<<dim3(HD / 128, KPAD_R / 64), blk, 0, stream>>>(
            rbH, rbL, BtH, BtL, nullptr, nullptr, rkH, rkL, KPAD_R, HD, DMODEL, HD);

        // ---- attention, chunked over groups ----
        for (int g0 = 0; g0 < NG; g0 += NGC) {
            k_vtconv_b<<<dim3(KLEN / 32, DH / 32, NGC), blk, 0, stream>>>(vH_, vL_, vtH, vtL, g0);
            k_score<false><<<dim3(KPAD_R / 128, QLEN / 128, NGC), blk, 0, stream>>>(
                qwH, qwL, khH, khL, sAc, g0);
            k_score<true><<<dim3(KPAD_R / 128, QLEN / 128, NGC), blk, 0, stream>>>(
                qrH, qrL, rkH, rkL, sAc, g0);
            k_softmax_p<<<dim3(QLEN, NGC), blk, 0, stream>>>(sAc, Pc);
            k_av<<<dim3(1, QLEN / 64, NGC), blk, 0, stream>>>(Pc, vtH, vtL, atH, atL, g0);
        }

        // delta(+delta2) = attnb @ o_w[l]   (split-K=2)
        k_wconv<<<dim3(DMODEL / 32, HD / 32), blk, 0, stream>>>(
            o_w + (size_t)l * HD * DMODEL, BtH, BtL, HD, DMODEL);
        k_mgemm<64, false, false, false, 2><<<dim3(DMODEL / 128, MQ / 64, 2), blk, 0, stream>>>(
            atH, atL, BtH, BtL, nullptr, delta, nullptr, nullptr, MQ, DMODEL, HD, DMODEL);

        k_add_ln<<<dim3(MQ), blk, 0, stream>>>(h, delta, delta2, ln1_g + (size_t)l * DMODEL,
                                               ln1_b + (size_t)l * DMODEL, hH, hL);

        // ffn = relu(h @ w1[l] + b1[l])
        k_wconv<<<dim3(DI / 32, DMODEL / 32), blk, 0, stream>>>(
            w1 + (size_t)l * DMODEL * DI, BtH, BtL, DMODEL, DI);
        k_mgemm<128, true, true, true, 1><<<dim3(DI / 128, MQ / 128), blk, 0, stream>>>(
            hH, hL, BtH, BtL, b1 + (size_t)l * DI, nullptr, ffnH, ffnL, MQ, DI, DMODEL, DI);

        // delta(+delta2) = ffn @ w2[l] + b2[l]   (split-K=2)
        k_wconv<<<dim3(DMODEL / 32, DI / 32), blk, 0, stream>>>(
            w2 + (size_t)l * DI * DMODEL, BtH, BtL, DI, DMODEL);
        k_mgemm<64, true, false, false, 2><<<dim3(DMODEL / 128, MQ / 64, 2), blk, 0, stream>>>(
            ffnH, ffnL, BtH, BtL, b2 + (size_t)l * DMODEL, delta, nullptr, nullptr,
            MQ, DMODEL, DI, DMODEL);

        k_add_ln<<<dim3(MQ), blk, 0, stream>>>(h, delta, delta2, ln2_g + (size_t)l * DMODEL,
                                               ln2_b + (size_t)l * DMODEL, hH, hL);
    }

    // out = h @ proj_w + proj_b     [2048,10000]
    k_wconv<<<dim3(NPAD_V / 32, DMODEL / 32), blk, 0, stream>>>(proj_w, BtH, BtL, DMODEL, NV);
    k_mgemm<128, true, false, false, 1><<<dim3(NPAD_V / 128, MQ / 128), blk, 0, stream>>>(
        hH, hL, BtH, BtL, proj_b, out, nullptr, nullptr, MQ, NV, DMODEL, NV);
}

// Round 4
// 5350.555 us; speedup vs baseline: 1.2166x; 1.2166x over previous
//
#include <hip/hip_runtime.h>
#include <stdint.h>

#define NLAYER 12
#define NH 12
#define DH 64
#define DMODEL 768
#define DI 3072
#define NV 10000
#define QLEN 512
#define MLEN 512
#define CLEN 32
#define BSZ 4
#define KLEN (CLEN + MLEN + QLEN)   // 1056
#define MQ (QLEN * BSZ)             // 2048
#define MK (KLEN * BSZ)             // 4224
#define H3 (3 * NH * DH)            // 2304
#define HD (NH * DH)                // 768
#define NG (BSZ * NH)               // 48 batched-attention groups
#define SROW ((size_t)QLEN * KLEN)  // score elems per group: 512*1056
#define KPAD_R 1152                 // rbuf/kh rows padded to 9*128
#define NPAD_V 10112                // proj cols padded to 79*128
#define NGC 24                      // attention group chunk

typedef __bf16 bf16;
typedef __bf16 bf16x8 __attribute__((ext_vector_type(8)));
typedef float f32x4 __attribute__((ext_vector_type(4)));

// async global -> LDS, 16B per lane (dest must be linear: wave base + lane*16)
__device__ __forceinline__ void gload16(const void* g, void* l) {
    __builtin_amdgcn_global_load_lds((const __attribute__((address_space(1))) void*)g,
                                     (__attribute__((address_space(3))) void*)l, 16, 0, 0);
}

// x = hi + lo split store (hi = RNE bf16(x); lo = bf16(x - hi))
__device__ __forceinline__ void split_store(float x, bf16* __restrict__ hp,
                                            bf16* __restrict__ lp, size_t off) {
    bf16 h = (bf16)x;
    hp[off] = h;
    lp[off] = (bf16)(x - (float)h);
}

// XCD-bijective + GRPM=4 row-grouped rasterization (T1 + panel-band L2 reuse)
__device__ __forceinline__ void raster(int& bx, int& by) {
    int gx = gridDim.x, gy = gridDim.y;
    int nwg = gx * gy;
    int wgid = blockIdx.y * gx + blockIdx.x;
    int q = nwg >> 3, r = nwg & 7;
    int xcd = wgid & 7, lin = wgid >> 3;
    int swz = (xcd < r ? xcd * (q + 1) : r * (q + 1) + (xcd - r) * q) + lin;
    int gsz = gx * 4;
    int grp = swz / gsz, rem = swz % gsz;
    int rows = gy - grp * 4;
    if (rows > 4) rows = 4;
    bx = rem / rows;
    by = grp * 4 + rem % rows;
}

// ---------------- embedding: h = emb[x] * sqrt(D) ----------------
__global__ __launch_bounds__(256) void k_embed(const int* __restrict__ x,
                                               const float* __restrict__ emb,
                                               float* __restrict__ h) {
    int idx = blockIdx.x * 256 + threadIdx.x;
    if (idx >= MQ * DMODEL) return;
    int row = idx / DMODEL;
    int d = idx % DMODEL;
    int tok = x[row];
    h[idx] = emb[(size_t)tok * DMODEL + d] * 27.712812921102035f;  // sqrt(768)
}

// ---------------- sinusoidal position embedding -> bf16 hi/lo planes [KPAD_R][D] ------------
__global__ __launch_bounds__(256) void k_posemb(bf16* __restrict__ rh, bf16* __restrict__ rl) {
    int idx = blockIdx.x * 256 + threadIdx.x;
    if (idx >= KPAD_R * DMODEL) return;
    int k = idx / DMODEL;
    int d = idx % DMODEL;
    float v = 0.0f;
    if (k < KLEN) {
        int pos = KLEN - 1 - k;
        int j = (d < DMODEL / 2) ? d : d - DMODEL / 2;
        double inv = exp(-((double)(2 * j) / (double)DMODEL) * log(10000.0));
        double s = (double)pos * inv;
        v = (d < DMODEL / 2) ? (float)sin(s) : (float)cos(s);
    }
    split_store(v, rh, rl, (size_t)idx);
}

// ---------------- zero the pad rows (1056..1151) of kh planes, once ----------------
__global__ __launch_bounds__(256) void k_zpad(bf16* __restrict__ khH, bf16* __restrict__ khL) {
    int idx = blockIdx.x * 256 + threadIdx.x;
    int tot = NG * (KPAD_R - KLEN) * DH;
    if (idx >= tot) return;
    int g = idx / ((KPAD_R - KLEN) * DH);
    int rem = idx % ((KPAD_R - KLEN) * DH);
    int jr = rem / DH, d = rem % DH;
    size_t off = ((size_t)g * KPAD_R + KLEN + jr) * DH + d;
    khH[off] = (bf16)0.0f;
    khL[off] = (bf16)0.0f;
}

// ---------------- concat [condition; mems[l]; h] -> bf16 hi/lo planes ----------------
__global__ __launch_bounds__(256) void k_concat(const float* __restrict__ cond,
                                                const float* __restrict__ mem_l,
                                                const float* __restrict__ h,
                                                bf16* __restrict__ catH,
                                                bf16* __restrict__ catL) {
    int idx = blockIdx.x * 256 + threadIdx.x;
    if (idx >= MK * DMODEL) return;
    int row = idx / DMODEL;
    int k = row / BSZ;
    float v;
    if (k < CLEN) v = cond[idx];
    else if (k < CLEN + MLEN) v = mem_l[idx - CLEN * BSZ * DMODEL];
    else v = h[idx - (CLEN + MLEN) * BSZ * DMODEL];
    split_store(v, catH, catL, (size_t)idx);
}

// ---------------- weight transpose + split: W[K][N] fp32 -> Bt_hi/lo[Npad][K] bf16 ----------
__global__ __launch_bounds__(256) void k_wconv(const float* __restrict__ W,
                                               bf16* __restrict__ Bh,
                                               bf16* __restrict__ Bl,
                                               int K, int N) {
    __shared__ float t[32][33];
    int n0 = blockIdx.x * 32, k0 = blockIdx.y * 32;
    int tc = threadIdx.x & 31, tr = threadIdx.x >> 5;
#pragma unroll
    for (int i = 0; i < 32; i += 8) {
        int n = n0 + tc;
        t[tr + i][tc] = (n < N) ? W[(size_t)(k0 + tr + i) * N + n] : 0.0f;
    }
    __syncthreads();
#pragma unroll
    for (int i = 0; i < 32; i += 8) {
        int n = n0 + tr + i;
        int k = k0 + tc;
        float x = t[tc][tr + i];
        size_t off = (size_t)n * K + k;
        bf16 h = (bf16)x;
        Bh[off] = h;
        Bl[off] = (bf16)(x - (float)h);
    }
}

// ---------------- split-bf16 MFMA GEMM: C[M,N] = A[M,K] @ B^T[N,K] (+bias)(+relu) -----------
template <int BM, bool BIAS, bool RELU, bool SPLITOUT, int SK>
__global__ __launch_bounds__(256) void k_mgemm(const bf16* __restrict__ Ahi,
                                               const bf16* __restrict__ Alo,
                                               const bf16* __restrict__ Bhi,
                                               const bf16* __restrict__ Blo,
                                               const float* __restrict__ bias,
                                               float* __restrict__ C,
                                               bf16* __restrict__ Chi,
                                               bf16* __restrict__ Clo,
                                               int M, int N, int K, int ldc) {
    constexpr int MI = (BM == 128) ? 4 : 2;
    __shared__ __align__(16) bf16 As[2][BM][32];
    __shared__ __align__(16) bf16 Bs[2][128][32];
    int bx, by;
    raster(bx, by);
    int z = (SK > 1) ? blockIdx.z : 0;
    int kb = K / SK;
    int kbeg = z * kb, kend = kbeg + kb;
    if (SK > 1) C += (size_t)z * M * ldc;
    int tid = threadIdx.x;
    int lane = tid & 63;
    int wave = tid >> 6;
    int bm = by * BM, bn = bx * 128;
    int wr = (wave >> 1) * (BM / 2), wc = (wave & 1) * 64;
    int fr = lane & 15;
    int fk = (lane >> 4) * 8;

    const f32x4 fzero = {0.f, 0.f, 0.f, 0.f};
    f32x4 acc[MI][4];
#pragma unroll
    for (int i = 0; i < MI; i++)
#pragma unroll
        for (int j = 0; j < 4; j++) acc[i][j] = fzero;

    int r0 = tid >> 2, p0 = (tid & 3) * 8;
    int r1 = r0 + 64, p1 = p0;

    for (int k0 = kbeg; k0 < kend; k0 += 32) {
        if (BM == 128) {
            gload16(Ahi + (size_t)(bm + r0) * K + k0 + p0, &As[0][r0][p0]);
            gload16(Ahi + (size_t)(bm + r1) * K + k0 + p1, &As[0][r1 & (BM - 1)][p1]);
            gload16(Alo + (size_t)(bm + r0) * K + k0 + p0, &As[1][r0][p0]);
            gload16(Alo + (size_t)(bm + r1) * K + k0 + p1, &As[1][r1 & (BM - 1)][p1]);
        } else {
            gload16(Ahi + (size_t)(bm + r0) * K + k0 + p0, &As[0][r0 & (BM - 1)][p0]);
            gload16(Alo + (size_t)(bm + r0) * K + k0 + p0, &As[1][r0 & (BM - 1)][p0]);
        }
        gload16(Bhi + (size_t)(bn + r0) * K + k0 + p0, &Bs[0][r0][p0]);
        gload16(Bhi + (size_t)(bn + r1) * K + k0 + p1, &Bs[0][r1][p1]);
        gload16(Blo + (size_t)(bn + r0) * K + k0 + p0, &Bs[1][r0][p0]);
        gload16(Blo + (size_t)(bn + r1) * K + k0 + p1, &Bs[1][r1][p1]);
        __syncthreads();

        bf16x8 ah[MI], al[MI], bh[4], bl[4];
#pragma unroll
        for (int mi = 0; mi < MI; mi++) {
            ah[mi] = *(const bf16x8*)&As[0][wr + mi * 16 + fr][fk];
            al[mi] = *(const bf16x8*)&As[1][wr + mi * 16 + fr][fk];
        }
#pragma unroll
        for (int ni = 0; ni < 4; ni++) {
            bh[ni] = *(const bf16x8*)&Bs[0][wc + ni * 16 + fr][fk];
            bl[ni] = *(const bf16x8*)&Bs[1][wc + ni * 16 + fr][fk];
        }
#pragma unroll
        for (int mi = 0; mi < MI; mi++)
#pragma unroll
            for (int ni = 0; ni < 4; ni++) {
                acc[mi][ni] = __builtin_amdgcn_mfma_f32_16x16x32_bf16(ah[mi], bh[ni], acc[mi][ni], 0, 0, 0);
                acc[mi][ni] = __builtin_amdgcn_mfma_f32_16x16x32_bf16(ah[mi], bl[ni], acc[mi][ni], 0, 0, 0);
                acc[mi][ni] = __builtin_amdgcn_mfma_f32_16x16x32_bf16(al[mi], bh[ni], acc[mi][ni], 0, 0, 0);
            }
        __syncthreads();
    }

#pragma unroll
    for (int mi = 0; mi < MI; mi++) {
        int rowb = bm + wr + mi * 16 + (lane >> 4) * 4;
#pragma unroll
        for (int ni = 0; ni < 4; ni++) {
            int col = bn + wc + ni * 16 + fr;
            if (col >= N) continue;
            float bv = (BIAS && z == 0) ? bias[col] : 0.0f;
#pragma unroll
            for (int r = 0; r < 4; r++) {
                int row = rowb + r;
                if (row >= M) continue;
                float xv = acc[mi][ni][r] + bv;
                if (RELU) xv = fmaxf(xv, 0.0f);
                size_t off = (size_t)row * ldc + col;
                if (SPLITOUT) {
                    bf16 hh = (bf16)xv;
                    Chi[off] = hh;
                    Clo[off] = (bf16)(xv - (float)hh);
                } else {
                    C[off] = xv;
                }
            }
        }
    }
}

// ---------------- qkv GEMM with fused split-plane epilogue ----------------
// MODE 0: Q gemm  (M=2048 h-rows, N=768)  -> qw/qr planes, (q+bias)*0.125
// MODE 1: KV gemm (M=4224 rows,  N=1536)  -> kh planes [g][1152][64], v planes [g][1056][64]
template <int MODE>
__global__ __launch_bounds__(256) void k_mgemm_qkv(const bf16* __restrict__ Ahi,
                                                   const bf16* __restrict__ Alo,
                                                   const bf16* __restrict__ Bhi,
                                                   const bf16* __restrict__ Blo,
                                                   const float* __restrict__ rwb,
                                                   const float* __restrict__ rrb,
                                                   bf16* __restrict__ P0H, bf16* __restrict__ P0L,
                                                   bf16* __restrict__ P1H, bf16* __restrict__ P1L) {
    constexpr int K = DMODEL;
    __shared__ __align__(16) bf16 As[2][128][32];
    __shared__ __align__(16) bf16 Bs[2][128][32];
    int bx, by;
    raster(bx, by);
    int tid = threadIdx.x;
    int lane = tid & 63;
    int wave = tid >> 6;
    int bm = by * 128, bn = bx * 128;
    int wr = (wave >> 1) * 64, wc = (wave & 1) * 64;
    int fr = lane & 15;
    int fk = (lane >> 4) * 8;

    const f32x4 fzero = {0.f, 0.f, 0.f, 0.f};
    f32x4 acc[4][4];
#pragma unroll
    for (int i = 0; i < 4; i++)
#pragma unroll
        for (int j = 0; j < 4; j++) acc[i][j] = fzero;

    int r0 = tid >> 2, p0 = (tid & 3) * 8;
    int r1 = r0 + 64, p1 = p0;

    for (int k0 = 0; k0 < K; k0 += 32) {
        gload16(Ahi + (size_t)(bm + r0) * K + k0 + p0, &As[0][r0][p0]);
        gload16(Ahi + (size_t)(bm + r1) * K + k0 + p1, &As[0][r1][p1]);
        gload16(Alo + (size_t)(bm + r0) * K + k0 + p0, &As[1][r0][p0]);
        gload16(Alo + (size_t)(bm + r1) * K + k0 + p1, &As[1][r1][p1]);
        gload16(Bhi + (size_t)(bn + r0) * K + k0 + p0, &Bs[0][r0][p0]);
        gload16(Bhi + (size_t)(bn + r1) * K + k0 + p1, &Bs[0][r1][p1]);
        gload16(Blo + (size_t)(bn + r0) * K + k0 + p0, &Bs[1][r0][p0]);
        gload16(Blo + (size_t)(bn + r1) * K + k0 + p1, &Bs[1][r1][p1]);
        __syncthreads();

        bf16x8 ah[4], al[4], bh[4], bl[4];
#pragma unroll
        for (int mi = 0; mi < 4; mi++) {
            ah[mi] = *(const bf16x8*)&As[0][wr + mi * 16 + fr][fk];
            al[mi] = *(const bf16x8*)&As[1][wr + mi * 16 + fr][fk];
        }
#pragma unroll
        for (int ni = 0; ni < 4; ni++) {
            bh[ni] = *(const bf16x8*)&Bs[0][wc + ni * 16 + fr][fk];
            bl[ni] = *(const bf16x8*)&Bs[1][wc + ni * 16 + fr][fk];
        }
#pragma unroll
        for (int mi = 0; mi < 4; mi++)
#pragma unroll
            for (int ni = 0; ni < 4; ni++) {
                acc[mi][ni] = __builtin_amdgcn_mfma_f32_16x16x32_bf16(ah[mi], bh[ni], acc[mi][ni], 0, 0, 0);
                acc[mi][ni] = __builtin_amdgcn_mfma_f32_16x16x32_bf16(ah[mi], bl[ni], acc[mi][ni], 0, 0, 0);
                acc[mi][ni] = __builtin_amdgcn_mfma_f32_16x16x32_bf16(al[mi], bh[ni], acc[mi][ni], 0, 0, 0);
            }
        __syncthreads();
    }

#pragma unroll
    for (int mi = 0; mi < 4; mi++) {
        int rowb = bm + wr + mi * 16 + (lane >> 4) * 4;
#pragma unroll
        for (int ni = 0; ni < 4; ni++) {
            int col = bn + wc + ni * 16 + fr;
#pragma unroll
            for (int r = 0; r < 4; r++) {
                int row = rowb + r;
                float xv = acc[mi][ni][r];
                int b = row & 3;
                if (MODE == 0) {
                    int i = row >> 2;
                    int g = b * NH + (col >> 6);
                    int d = col & 63;
                    size_t off = ((size_t)g * QLEN + i) * DH + d;
                    split_store((xv + rwb[col]) * 0.125f, P0H, P0L, off);
                    split_store((xv + rrb[col]) * 0.125f, P1H, P1L, off);
                } else {
                    int j = row >> 2;
                    if (col < HD) {
                        int g = b * NH + (col >> 6);
                        int d = col & 63;
                        split_store(xv, P0H, P0L, ((size_t)g * KPAD_R + j) * DH + d);
                    } else {
                        int c2 = col - HD;
                        int g = b * NH + (c2 >> 6);
                        int d = c2 & 63;
                        split_store(xv, P1H, P1L, ((size_t)g * KLEN + j) * DH + d);
                    }
                }
            }
        }
    }
}

// ---------------- bf16 V transpose: v[g][1056][64] -> vt[gl][64][1056] ----------------
__global__ __launch_bounds__(256) void k_vtconv_b(const bf16* __restrict__ vH,
                                                  const bf16* __restrict__ vL,
                                                  bf16* __restrict__ vtH,
                                                  bf16* __restrict__ vtL,
                                                  int g0) {
    __shared__ bf16 th[32][33], tl[32][33];
    int gl = blockIdx.z;
    int g = g0 + gl;
    int j0 = blockIdx.x * 32, d0 = blockIdx.y * 32;
    int tc = threadIdx.x & 31, tr = threadIdx.x >> 5;
#pragma unroll
    for (int i = 0; i < 32; i += 8) {
        size_t src = ((size_t)g * KLEN + j0 + tr + i) * DH + d0 + tc;
        th[tr + i][tc] = vH[src];
        tl[tr + i][tc] = vL[src];
    }
    __syncthreads();
#pragma unroll
    for (int i = 0; i < 32; i += 8) {
        size_t dst = ((size_t)gl * DH + d0 + tr + i) * KLEN + j0 + tc;
        vtH[dst] = th[tc][tr + i];
        vtL[dst] = tl[tc][tr + i];
    }
}

// ---------------- BDt GEMM (MFMA, split-bf16): BDt[gl][i][t] = qr_i . rk_t ----------------
// t-space, no scatter. Tile skipped iff no (i,t) with t >= 511-i (bn+bm <= 256).
__global__ __launch_bounds__(256) void k_bdt(const bf16* __restrict__ QH,
                                             const bf16* __restrict__ QL,
                                             const bf16* __restrict__ RH,
                                             const bf16* __restrict__ RL,
                                             float* __restrict__ BDt,
                                             int g0) {
    int bm = blockIdx.y * 128, bn = blockIdx.x * 128;
    if (bn + bm <= 256) return;
    int gl = blockIdx.z;
    int g = g0 + gl;
    int n = g % NH;
    const bf16* Ah = QH + (size_t)g * QLEN * DH;
    const bf16* Al = QL + (size_t)g * QLEN * DH;
    const bf16* Bh = RH + n * DH;
    const bf16* Bl = RL + n * DH;
    float* C = BDt + (size_t)gl * SROW;

    __shared__ __align__(16) bf16 As[2][128][32];
    __shared__ __align__(16) bf16 Bs[2][128][32];
    int tid = threadIdx.x;
    int lane = tid & 63;
    int wave = tid >> 6;
    int wr = (wave >> 1) * 64, wc = (wave & 1) * 64;
    int fr = lane & 15;
    int fk = (lane >> 4) * 8;

    const f32x4 fzero = {0.f, 0.f, 0.f, 0.f};
    f32x4 acc[4][4];
#pragma unroll
    for (int i = 0; i < 4; i++)
#pragma unroll
        for (int j = 0; j < 4; j++) acc[i][j] = fzero;

    int r0 = tid >> 2, p0 = (tid & 3) * 8;
    int r1 = r0 + 64, p1 = p0;

#pragma unroll
    for (int k0 = 0; k0 < DH; k0 += 32) {
        gload16(Ah + (size_t)(bm + r0) * DH + k0 + p0, &As[0][r0][p0]);
        gload16(Ah + (size_t)(bm + r1) * DH + k0 + p1, &As[0][r1][p1]);
        gload16(Al + (size_t)(bm + r0) * DH + k0 + p0, &As[1][r0][p0]);
        gload16(Al + (size_t)(bm + r1) * DH + k0 + p1, &As[1][r1][p1]);
        gload16(Bh + (size_t)(bn + r0) * HD + k0 + p0, &Bs[0][r0][p0]);
        gload16(Bh + (size_t)(bn + r1) * HD + k0 + p1, &Bs[0][r1][p1]);
        gload16(Bl + (size_t)(bn + r0) * HD + k0 + p0, &Bs[1][r0][p0]);
        gload16(Bl + (size_t)(bn + r1) * HD + k0 + p1, &Bs[1][r1][p1]);
        __syncthreads();

        bf16x8 ah[4], al[4], bh[4], bl[4];
#pragma unroll
        for (int mi = 0; mi < 4; mi++) {
            ah[mi] = *(const bf16x8*)&As[0][wr + mi * 16 + fr][fk];
            al[mi] = *(const bf16x8*)&As[1][wr + mi * 16 + fr][fk];
        }
#pragma unroll
        for (int ni = 0; ni < 4; ni++) {
            bh[ni] = *(const bf16x8*)&Bs[0][wc + ni * 16 + fr][fk];
            bl[ni] = *(const bf16x8*)&Bs[1][wc + ni * 16 + fr][fk];
        }
#pragma unroll
        for (int mi = 0; mi < 4; mi++)
#pragma unroll
            for (int ni = 0; ni < 4; ni++) {
                acc[mi][ni] = __builtin_amdgcn_mfma_f32_16x16x32_bf16(ah[mi], bh[ni], acc[mi][ni], 0, 0, 0);
                acc[mi][ni] = __builtin_amdgcn_mfma_f32_16x16x32_bf16(ah[mi], bl[ni], acc[mi][ni], 0, 0, 0);
                acc[mi][ni] = __builtin_amdgcn_mfma_f32_16x16x32_bf16(al[mi], bh[ni], acc[mi][ni], 0, 0, 0);
            }
        __syncthreads();
    }

#pragma unroll
    for (int mi = 0; mi < 4; mi++) {
        int rowb = bm + wr + mi * 16 + (lane >> 4) * 4;
#pragma unroll
        for (int ni = 0; ni < 4; ni++) {
            int t = bn + wc + ni * 16 + fr;
            if (t >= KLEN) continue;
#pragma unroll
            for (int r = 0; r < 4; r++) {
                int i = rowb + r;
                C[(size_t)i * KLEN + t] = acc[mi][ni][r];
            }
        }
    }
}

// ---------------- fused flash attention: AC + BD-gather + online softmax + PV ----------------
// block = (group gl, 64 q-rows). K/V tiles of 64 streamed through swizzled LDS.
// O accumulated in registers; single normalize + split-store epilogue.
__global__ __launch_bounds__(256) void k_flash(const bf16* __restrict__ qwH, const bf16* __restrict__ qwL,
                                               const bf16* __restrict__ khH, const bf16* __restrict__ khL,
                                               const bf16* __restrict__ vtH, const bf16* __restrict__ vtL,
                                               const float* __restrict__ BDt,
                                               bf16* __restrict__ atH, bf16* __restrict__ atL,
                                               int g0) {
    __shared__ __align__(16) bf16 LQ[2][64][64];
    __shared__ __align__(16) bf16 LK[2][64][64];
    __shared__ __align__(16) bf16 LV[2][64][64];
    __shared__ __align__(16) bf16 LP[64][64];
    int gl = blockIdx.y;
    int g = g0 + gl;
    int b = g / NH, n = g % NH;
    int i0 = blockIdx.x * 64;
    int tid = threadIdx.x, lane = tid & 63, w = tid >> 6;
    int fr = lane & 15, fq = lane >> 4, fk = fq * 8;

    // stage qw block (64x64) hi/lo, linear
    {
        const bf16* q0 = qwH + ((size_t)g * QLEN + i0) * DH;
        const bf16* q1 = qwL + ((size_t)g * QLEN + i0) * DH;
        int c0 = tid, c1 = tid + 256;
        gload16(q0 + (c0 >> 3) * DH + (c0 & 7) * 8, &LQ[0][c0 >> 3][(c0 & 7) * 8]);
        gload16(q0 + (c1 >> 3) * DH + (c1 & 7) * 8, &LQ[0][c1 >> 3][(c1 & 7) * 8]);
        gload16(q1 + (c0 >> 3) * DH + (c0 & 7) * 8, &LQ[1][c0 >> 3][(c0 & 7) * 8]);
        gload16(q1 + (c1 >> 3) * DH + (c1 & 7) * 8, &LQ[1][c1 >> 3][(c1 & 7) * 8]);
    }
    __syncthreads();
    bf16x8 aqh[2], aql[2];
    aqh[0] = *(const bf16x8*)&LQ[0][w * 16 + fr][fk];
    aqh[1] = *(const bf16x8*)&LQ[0][w * 16 + fr][32 + fk];
    aql[0] = *(const bf16x8*)&LQ[1][w * 16 + fr][fk];
    aql[1] = *(const bf16x8*)&LQ[1][w * 16 + fr][32 + fk];

    const f32x4 fz = {0.f, 0.f, 0.f, 0.f};
    f32x4 ao[4] = {fz, fz, fz, fz};
    float m[4] = {-3e38f, -3e38f, -3e38f, -3e38f};
    float l[4] = {0.f, 0.f, 0.f, 0.f};

    const bf16* kb0 = khH + (size_t)g * KPAD_R * DH;
    const bf16* kb1 = khL + (size_t)g * KPAD_R * DH;
    const bf16* vb0 = vtH + (size_t)gl * DH * KLEN;
    const bf16* vb1 = vtL + (size_t)gl * DH * KLEN;
    const float* bdp = BDt + (size_t)gl * SROW;

    int ntiles = (i0 + 607) / 64 + 1;
    for (int jt = 0; jt < ntiles; jt++) {
        int j0 = jt * 64;
        // stage K/V tiles: linear dest + inverse-swizzled source (rule #21)
        {
            int c0 = tid, c1 = tid + 256;
            int r0 = c0 >> 3, cb0 = (c0 & 7) * 16, s0 = (cb0 ^ ((r0 & 7) << 4)) >> 1;
            int r1 = c1 >> 3, cb1 = (c1 & 7) * 16, s1 = (cb1 ^ ((r1 & 7) << 4)) >> 1;
            gload16(kb0 + (size_t)(j0 + r0) * DH + s0, &LK[0][r0][cb0 >> 1]);
            gload16(kb0 + (size_t)(j0 + r1) * DH + s1, &LK[0][r1][cb1 >> 1]);
            gload16(kb1 + (size_t)(j0 + r0) * DH + s0, &LK[1][r0][cb0 >> 1]);
            gload16(kb1 + (size_t)(j0 + r1) * DH + s1, &LK[1][r1][cb1 >> 1]);
            gload16(vb0 + (size_t)r0 * KLEN + j0 + s0, &LV[0][r0][cb0 >> 1]);
            gload16(vb0 + (size_t)r1 * KLEN + j0 + s1, &LV[0][r1][cb1 >> 1]);
            gload16(vb1 + (size_t)r0 * KLEN + j0 + s0, &LV[1][r0][cb0 >> 1]);
            gload16(vb1 + (size_t)r1 * KLEN + j0 + s1, &LV[1][r1][cb1 >> 1]);
        }
        // BD gather (t = j + 511 - i; clamped reads only on masked positions)
        float bd[4][4];
#pragma unroll
        for (int ni = 0; ni < 4; ni++) {
            int j = j0 + ni * 16 + fr;
#pragma unroll
            for (int r = 0; r < 4; r++) {
                int i = i0 + w * 16 + fq * 4 + r;
                int t = j + (QLEN - 1) - i;
                if (t > KLEN - 1) t = KLEN - 1;
                bd[ni][r] = bdp[(size_t)i * KLEN + t];
            }
        }
        __syncthreads();
        // S = qw.K (split-bf16 MFMA) + BD, masked
        f32x4 sa[4] = {fz, fz, fz, fz};
#pragma unroll
        for (int k0 = 0; k0 < 2; k0++) {
#pragma unroll
            for (int ni = 0; ni < 4; ni++) {
                int row = ni * 16 + fr;
                int cb = ((k0 * 32 + fk) * 2) ^ ((row & 7) << 4);
                bf16x8 bh = *(const bf16x8*)((const char*)LK[0] + row * 128 + cb);
                bf16x8 bl = *(const bf16x8*)((const char*)LK[1] + row * 128 + cb);
                sa[ni] = __builtin_amdgcn_mfma_f32_16x16x32_bf16(aqh[k0], bh, sa[ni], 0, 0, 0);
                sa[ni] = __builtin_amdgcn_mfma_f32_16x16x32_bf16(aqh[k0], bl, sa[ni], 0, 0, 0);
                sa[ni] = __builtin_amdgcn_mfma_f32_16x16x32_bf16(aql[k0], bh, sa[ni], 0, 0, 0);
            }
        }
        float mx[4] = {-3e38f, -3e38f, -3e38f, -3e38f};
        float pe[4][4];
#pragma unroll
        for (int ni = 0; ni < 4; ni++) {
            int j = j0 + ni * 16 + fr;
#pragma unroll
            for (int r = 0; r < 4; r++) {
                int i = i0 + w * 16 + fq * 4 + r;
                float s = sa[ni][r] + bd[ni][r];
                s = (j - i <= CLEN + MLEN && j < KLEN) ? s : -1e30f;
                pe[ni][r] = s;
                mx[r] = fmaxf(mx[r], s);
            }
        }
#pragma unroll
        for (int off = 1; off < 16; off <<= 1) {
#pragma unroll
            for (int r = 0; r < 4; r++) mx[r] = fmaxf(mx[r], __shfl_xor(mx[r], off, 16));
        }
        float al[4], rs[4];
#pragma unroll
        for (int r = 0; r < 4; r++) {
            float mn = fmaxf(m[r], mx[r]);
            al[r] = __expf(m[r] - mn);
            m[r] = mn;
            rs[r] = 0.f;
        }
#pragma unroll
        for (int ni = 0; ni < 4; ni++)
#pragma unroll
            for (int r = 0; r < 4; r++) {
                float e = __expf(pe[ni][r] - m[r]);
                pe[ni][r] = e;
                rs[r] += e;
            }
#pragma unroll
        for (int off = 1; off < 16; off <<= 1) {
#pragma unroll
            for (int r = 0; r < 4; r++) rs[r] += __shfl_xor(rs[r], off, 16);
        }
        f32x4 av;
#pragma unroll
        for (int r = 0; r < 4; r++) {
            l[r] = l[r] * al[r] + rs[r];
            av[r] = al[r];
        }
#pragma unroll
        for (int d0 = 0; d0 < 4; d0++) ao[d0] *= av;
        // P -> bf16 -> LDS (swizzled both sides)
#pragma unroll
        for (int ni = 0; ni < 4; ni++)
#pragma unroll
            for (int r = 0; r < 4; r++) {
                int row = w * 16 + fq * 4 + r;
                int byt = row * 128 + (((ni * 16 + fr) * 2) ^ ((row & 7) << 4));
                *(bf16*)((char*)LP + byt) = (bf16)pe[ni][r];
            }
        asm volatile("s_waitcnt lgkmcnt(0)" ::: "memory");
        __builtin_amdgcn_sched_barrier(0);
        // O += P * V (P hi-only; V hi+lo)
#pragma unroll
        for (int k0 = 0; k0 < 2; k0++) {
            int prow = w * 16 + fr;
            int pb = prow * 128 + (((k0 * 32 + fk) * 2) ^ ((prow & 7) << 4));
            bf16x8 pa = *(const bf16x8*)((const char*)LP + pb);
#pragma unroll
            for (int d0 = 0; d0 < 4; d0++) {
                int vrow = d0 * 16 + fr;
                int vbyt = vrow * 128 + (((k0 * 32 + fk) * 2) ^ ((vrow & 7) << 4));
                bf16x8 vh = *(const bf16x8*)((const char*)LV[0] + vbyt);
                bf16x8 vl = *(const bf16x8*)((const char*)LV[1] + vbyt);
                ao[d0] = __builtin_amdgcn_mfma_f32_16x16x32_bf16(pa, vh, ao[d0], 0, 0, 0);
                ao[d0] = __builtin_amdgcn_mfma_f32_16x16x32_bf16(pa, vl, ao[d0], 0, 0, 0);
            }
        }
        __syncthreads();
    }
    f32x4 iv;
#pragma unroll
    for (int r = 0; r < 4; r++) iv[r] = 1.0f / l[r];
#pragma unroll
    for (int d0 = 0; d0 < 4; d0++) {
        ao[d0] *= iv;
#pragma unroll
        for (int r = 0; r < 4; r++) {
            int i = i0 + w * 16 + fq * 4 + r;
            int d = d0 * 16 + fr;
            size_t off = (size_t)(i * BSZ + b) * HD + n * DH + d;
            split_store(ao[d0][r], atH, atL, off);
        }
    }
}

// ---------------- h = LN(h + d0 + d1); also emit bf16 hi/lo planes of h ----------------
__global__ __launch_bounds__(256) void k_add_ln(float* __restrict__ h,
                                                const float* __restrict__ d0,
                                                const float* __restrict__ d1,
                                                const float* __restrict__ g,
                                                const float* __restrict__ bta,
                                                bf16* __restrict__ hH,
                                                bf16* __restrict__ hL) {
    __shared__ float xs[DMODEL];
    __shared__ float red[256];
    int row = blockIdx.x;
    int tid = threadIdx.x;
    float* hr = h + (size_t)row * DMODEL;
    const float* dr0 = d0 + (size_t)row * DMODEL;
    const float* dr1 = d1 + (size_t)row * DMODEL;
    float s = 0.f;
    for (int d = tid; d < DMODEL; d += 256) {
        float v = hr[d] + dr0[d] + dr1[d];
        xs[d] = v;
        s += v;
    }
    red[tid] = s;
    __syncthreads();
    for (int st = 128; st > 0; st >>= 1) {
        if (tid < st) red[tid] += red[tid + st];
        __syncthreads();
    }
    float mean = red[0] * (1.0f / DMODEL);
    __syncthreads();
    float v2 = 0.f;
    for (int d = tid; d < DMODEL; d += 256) {
        float t = xs[d] - mean;
        v2 += t * t;
    }
    red[tid] = v2;
    __syncthreads();
    for (int st = 128; st > 0; st >>= 1) {
        if (tid < st) red[tid] += red[tid + st];
        __syncthreads();
    }
    float inv = rsqrtf(red[0] * (1.0f / DMODEL) + 1e-5f);
    for (int d = tid; d < DMODEL; d += 256) {
        float y = (xs[d] - mean) * inv * g[d] + bta[d];
        hr[d] = y;
        split_store(y, hH, hL, (size_t)row * DMODEL + d);
    }
}

extern "C" void kernel_launch(void* const* d_in, const int* in_sizes, int n_in,
                              void* d_out, int out_size, void* d_ws, size_t ws_size,
                              hipStream_t stream) {
    const int* x = (const int*)d_in[0];
    const float* condition = (const float*)d_in[1];
    const float* mems = (const float*)d_in[2];
    const float* emb = (const float*)d_in[3];
    const float* qkv_w = (const float*)d_in[4];
    const float* r_net_w = (const float*)d_in[5];
    const float* o_w = (const float*)d_in[6];
    const float* ln1_g = (const float*)d_in[7];
    const float* ln1_b = (const float*)d_in[8];
    const float* w1 = (const float*)d_in[9];
    const float* b1 = (const float*)d_in[10];
    const float* w2 = (const float*)d_in[11];
    const float* b2 = (const float*)d_in[12];
    const float* ln2_g = (const float*)d_in[13];
    const float* ln2_b = (const float*)d_in[14];
    const float* r_w_bias = (const float*)d_in[15];
    const float* r_r_bias = (const float*)d_in[16];
    const float* proj_w = (const float*)d_in[17];
    const float* proj_b = (const float*)d_in[18];
    float* out = (float*)d_out;

    // ---- fp32 region ----
    float* ws = (float*)d_ws;
    float* h = ws;                                    // 2048*768
    float* delta = h + (size_t)MQ * DMODEL;           // 2 x 2048*768 (split-K pair)
    float* delta2 = delta + (size_t)MQ * DMODEL;

    // ---- persistent bf16 planes ----
    bf16* pb = (bf16*)(delta2 + (size_t)MQ * DMODEL);
    bf16* rbH = pb; pb += (size_t)KPAD_R * DMODEL;
    bf16* rbL = pb; pb += (size_t)KPAD_R * DMODEL;
    bf16* rkH = pb; pb += (size_t)KPAD_R * DMODEL;
    bf16* rkL = pb; pb += (size_t)KPAD_R * DMODEL;
    bf16* atH = pb; pb += (size_t)MQ * HD;
    bf16* atL = pb; pb += (size_t)MQ * HD;
    bf16* qwH = pb; pb += (size_t)NG * QLEN * DH;
    bf16* qwL = pb; pb += (size_t)NG * QLEN * DH;
    bf16* qrH = pb; pb += (size_t)NG * QLEN * DH;
    bf16* qrL = pb; pb += (size_t)NG * QLEN * DH;
    bf16* khH = pb; pb += (size_t)NG * KPAD_R * DH;
    bf16* khL = pb; pb += (size_t)NG * KPAD_R * DH;
    bf16* vH_ = pb; pb += (size_t)NG * KLEN * DH;
    bf16* vL_ = pb; pb += (size_t)NG * KLEN * DH;

    // ---- alias region R: GEMM-phase planes XOR attention-phase {BDt, vt} ----
    bf16* R = pb;
    bf16* BtH = R;
    bf16* BtL = BtH + (size_t)NPAD_V * DMODEL;
    bf16* ffnH = BtL + (size_t)NPAD_V * DMODEL;
    bf16* ffnL = ffnH + (size_t)MQ * DI;
    bf16* catH = ffnL + (size_t)MQ * DI;
    bf16* catL = catH + (size_t)MK * DMODEL;
    bf16* hH = catL + (size_t)MK * DMODEL;
    bf16* hL = hH + (size_t)MQ * DMODEL;
    // attention overlay (dead outside vtconv..flash window; ends before hH)
    float* BDt = (float*)R;                           // NGC*SROW fp32 (51.9MB)
    bf16* vtH = (bf16*)(BDt + (size_t)NGC * SROW);    // NGC*64*1056
    bf16* vtL = vtH + (size_t)NGC * DH * KLEN;

    dim3 blk(256);
    k_embed<<<dim3((MQ * DMODEL + 255) / 256), blk, 0, stream>>>(x, emb, h);
    k_posemb<<<dim3((KPAD_R * DMODEL + 255) / 256), blk, 0, stream>>>(rbH, rbL);
    k_zpad<<<dim3((NG * (KPAD_R - KLEN) * DH + 255) / 256), blk, 0, stream>>>(khH, khL);

    for (int l = 0; l < NLAYER; l++) {
        k_concat<<<dim3((MK * DMODEL + 255) / 256), blk, 0, stream>>>(
            condition, mems + (size_t)l * MLEN * BSZ * DMODEL, h, catH, catL);

        // qkv projection, fused split-plane epilogues
        k_wconv<<<dim3(H3 / 32, DMODEL / 32), blk, 0, stream>>>(
            qkv_w + (size_t)l * DMODEL * H3, BtH, BtL, DMODEL, H3);
        k_mgemm_qkv<1><<<dim3((2 * HD) / 128, MK / 128), blk, 0, stream>>>(
            catH, catL, BtH + (size_t)HD * DMODEL, BtL + (size_t)HD * DMODEL,
            nullptr, nullptr, khH, khL, vH_, vL_);
        k_mgemm_qkv<0><<<dim3(HD / 128, MQ / 128), blk, 0, stream>>>(
            catH + (size_t)(CLEN + MLEN) * BSZ * DMODEL, catL + (size_t)(CLEN + MLEN) * BSZ * DMODEL,
            BtH, BtL, r_w_bias, r_r_bias, qwH, qwL, qrH, qrL);

        // rk = r @ r_net_w[l] -> split planes [1152][768]
        k_wconv<<<dim3(HD / 32, DMODEL / 32), blk, 0, stream>>>(
            r_net_w + (size_t)l * DMODEL * HD, BtH, BtL, DMODEL, HD);
        k_mgemm<64, false, false, true, 1><<<dim3(HD / 128, KPAD_R / 64), blk, 0, stream>>>(
            rbH, rbL, BtH, BtL, nullptr, nullptr, rkH, rkL, KPAD_R, HD, DMODEL, HD);

        // ---- attention (fused flash), chunked over groups ----
        for (int g0 = 0; g0 < NG; g0 += NGC) {
            k_vtconv_b<<<dim3(KLEN / 32, DH / 32, NGC), blk, 0, stream>>>(vH_, vL_, vtH, vtL, g0);
            k_bdt<<<dim3(KPAD_R / 128, QLEN / 128, NGC), blk, 0, stream>>>(
                qrH, qrL, rkH, rkL, BDt, g0);
            k_flash<<<dim3(QLEN / 64, NGC), blk, 0, stream>>>(
                qwH, qwL, khH, khL, vtH, vtL, BDt, atH, atL, g0);
        }

        // delta(+delta2) = attnb @ o_w[l]   (split-K=2)
        k_wconv<<<dim3(DMODEL / 32, HD / 32), blk, 0, stream>>>(
            o_w + (size_t)l * HD * DMODEL, BtH, BtL, HD, DMODEL);
        k_mgemm<64, false, false, false, 2><<<dim3(DMODEL / 128, MQ / 64, 2), blk, 0, stream>>>(
            atH, atL, BtH, BtL, nullptr, delta, nullptr, nullptr, MQ, DMODEL, HD, DMODEL);

        k_add_ln<<<dim3(MQ), blk, 0, stream>>>(h, delta, delta2, ln1_g + (size_t)l * DMODEL,
                                               ln1_b + (size_t)l * DMODEL, hH, hL);

        // ffn = relu(h @ w1[l] + b1[l])
        k_wconv<<<dim3(DI / 32, DMODEL / 32), blk, 0, stream>>>(
            w1 + (size_t)l * DMODEL * DI, BtH, BtL, DMODEL, DI);
        k_mgemm<128, true, true, true, 1><<<dim3(DI / 128, MQ / 128), blk, 0, stream>>>(
            hH, hL, BtH, BtL, b1 + (size_t)l * DI, nullptr, ffnH, ffnL, MQ, DI, DMODEL, DI);

        // delta(+delta2) = ffn @ w2[l] + b2[l]   (split-K=2)
        k_wconv<<<dim3(DMODEL / 32, DI / 32), blk, 0, stream>>>(
            w2 + (size_t)l * DI * DMODEL, BtH, BtL, DI, DMODEL);
        k_mgemm<64, true, false, false, 2><<<dim3(DMODEL / 128, MQ / 64, 2), blk, 0, stream>>>(
            ffnH, ffnL, BtH, BtL, b2 + (size_t)l * DMODEL, delta, nullptr, nullptr,
            MQ, DMODEL, DI, DMODEL);

        k_add_ln<<<dim3(MQ), blk, 0, stream>>>(h, delta, delta2, ln2_g + (size_t)l * DMODEL,
                                               ln2_b + (size_t)l * DMODEL, hH, hL);
    }

    // out = h @ proj_w + proj_b     [2048,10000]
    k_wconv<<<dim3(NPAD_V / 32, DMODEL / 32), blk, 0, stream>>>(proj_w, BtH, BtL, DMODEL, NV);
    k_mgemm<128, true, false, false, 1><<<dim3(NPAD_V / 128, MQ / 128), blk, 0, stream>>>(
        hH, hL, BtH, BtL, proj_b, out, nullptr, nullptr, MQ, NV, DMODEL, NV);
}